// Round 11
// baseline (782.666 us; speedup 1.0000x reference)
//
#include <hip/hip_runtime.h>
#include <cstdint>
#include <cstddef>

namespace {

constexpr int TS  = 512;   // timesteps
constexpr int BB  = 1024;  // batch
constexpr int IND = 32;    // input dim
constexpr int H0D = 128;   // layer0 hidden
constexpr int H1D = 64;    // layer1 hidden
constexpr int RPW = 4;     // batch rows per WG -> 256 WGs
constexpr int S0  = 132;   // padded LDS row stride (floats) for 128-wide state
constexpr int S1  = 68;    // padded LDS row stride (floats) for 64-wide state
constexpr int NT  = 768;   // 12 waves: 8 producer (1 slice each) + 4 consumer

typedef float f32x4 __attribute__((ext_vector_type(4)));
typedef __bf16 bf16x8 __attribute__((ext_vector_type(8)));

__device__ __forceinline__ float rcpf(float x) {
    float r; asm("v_rcp_f32 %0, %1" : "=v"(r) : "v"(x)); return r;
}
__device__ __forceinline__ float sigm(float z) { return rcpf(1.0f + __expf(-z)); }
__device__ __forceinline__ float tanh_f(float z) {
    return fmaf(-2.0f, rcpf(__expf(2.0f * z) + 1.0f), 1.0f);  // inf-safe both ends
}
__device__ __forceinline__ bf16x8 cvt8(f32x4 a, f32x4 b) {
    bf16x8 r;
    r[0] = (__bf16)a[0]; r[1] = (__bf16)a[1]; r[2] = (__bf16)a[2]; r[3] = (__bf16)a[3];
    r[4] = (__bf16)b[0]; r[5] = (__bf16)b[1]; r[6] = (__bf16)b[2]; r[7] = (__bf16)b[3];
    return r;
}
__device__ __forceinline__ bf16x8 ld8(const float* p) {
    f32x4 a = *(const f32x4*)p;
    f32x4 b = *(const f32x4*)(p + 4);
    return cvt8(a, b);
}
__device__ __forceinline__ f32x4 mfma16(bf16x8 a, bf16x8 b, f32x4 c) {
    return __builtin_amdgcn_mfma_f32_16x16x32_bf16(a, b, c, 0, 0, 0);
}

// 256 WGs x 4 batch rows, 12 waves (768 thr), 1 block/CU -> 3 waves/SIMD.
// Single change vs R9 (602us verified): finer role split for occupancy.
//   waves 0-7:  producer, ONE layer0 slice each (21 frags ~84 VGPR wt)
//   waves 8-11: consumer, layer1 full-K slice (28 frags ~112 VGPR wt)
// Same verified R9 skeleton: fp32 padded LDS state (one writer lane per
// dword), ONE barrier per step, producers run ahead into t+1 after B1.
__global__ __launch_bounds__(NT, 3) void resid_lstm(
    const float* __restrict__ x,
    const float* __restrict__ h0i, const float* __restrict__ c0i,
    const float* __restrict__ h1i, const float* __restrict__ c1i,
    const float* __restrict__ Wih0, const float* __restrict__ Whh0,
    const float* __restrict__ bih0, const float* __restrict__ bhh0,
    const float* __restrict__ Ws0,  const float* __restrict__ bs0v,
    const float* __restrict__ Wih1, const float* __restrict__ Whh1,
    const float* __restrict__ bih1, const float* __restrict__ bhh1,
    const float* __restrict__ Ws1,  const float* __restrict__ bs1v,
    float* __restrict__ out)
{
    const int tid  = threadIdx.x;
    const int lane = tid & 63;
    const int w    = tid >> 6;        // wave 0..11
    const int fr   = lane & 15;       // A-row index within tile / C col (unit)
    const int fk   = lane >> 4;       // k-group; also this lane's batch row
    const int row0 = blockIdx.x * RPW;
    const bool prod = (w < 8);

    __shared__ __align__(16) float h0f[2][RPW][S0];   // h0 state (fp32)
    __shared__ __align__(16) float i1f[2][RPW][S0];   // clip(h0) (fp32)
    __shared__ __align__(16) float h1q[2][RPW][S1];   // h1 state (fp32)

    // zero ALL LDS first (separate barrier so init writes can't race it)
    for (int i = tid; i < 2 * RPW * S0; i += NT) {
        (&h0f[0][0][0])[i] = 0.f;
        (&i1f[0][0][0])[i] = 0.f;
    }
    for (int i = tid; i < 2 * RPW * S1; i += NT)
        (&h1q[0][0][0])[i] = 0.f;
    __syncthreads();

    bf16x8 WF[28];    // producer uses 21 (4 gates x 5 + ws0); consumer 28
    float BZ[5];      // folded biases
    float CS = 0.f;   // c-state: producer c0; consumer c1

    if (prod) {
        const int u = w*16 + fr;
        #pragma unroll
        for (int g = 0; g < 4; ++g) {
            const int r0 = g*H0D + u;             // gate order i,f,g,o
            WF[g*5] = ld8(Wih0 + r0*IND + fk*8);
            #pragma unroll
            for (int ks = 0; ks < 4; ++ks)
                WF[g*5 + 1 + ks] = ld8(Whh0 + r0*H0D + ks*32 + fk*8);
            BZ[g] = bih0[r0] + bhh0[r0];
        }
        WF[20] = ld8(Ws0 + u*IND + fk*8);
        BZ[4] = bs0v[u];
        CS = c0i[(size_t)(row0 + fk)*H0D + u];
    } else {
        const int u1 = (w - 8)*16 + fr;
        #pragma unroll
        for (int g = 0; g < 4; ++g) {
            const int r1 = g*H1D + u1;
            #pragma unroll
            for (int ks = 0; ks < 4; ++ks)
                WF[g*6 + ks] = ld8(Wih1 + r1*H0D + ks*32 + fk*8);
            #pragma unroll
            for (int k2 = 0; k2 < 2; ++k2)
                WF[g*6 + 4 + k2] = ld8(Whh1 + r1*H1D + k2*32 + fk*8);
            BZ[g] = bih1[r1] + bhh1[r1];
        }
        #pragma unroll
        for (int ks = 0; ks < 4; ++ks)
            WF[24 + ks] = ld8(Ws1 + u1*H0D + ks*32 + fk*8);
        BZ[4] = bs1v[u1];
        CS = c1i[(size_t)(row0 + fk)*H1D + u1];
    }

    // initial hidden states -> LDS fp32 (both read at t=0 from buffer 0)
    if (tid < RPW * H0D) {
        const int u = tid & 127, b2 = tid >> 7;
        h0f[0][b2][u] = h0i[(size_t)(row0 + b2)*H0D + u];
    }
    if (tid < RPW * H1D) {
        const int u = tid & 63, b2 = tid >> 6;
        h1q[0][b2][u] = h1i[(size_t)(row0 + b2)*H1D + u];
    }

    const int arow = fr >> 2;   // this lane's A-row batch index (rows duplicated x4)

    const float* xbase = x + ((size_t)row0 + arow)*IND + fk*8;
    f32x4 xa = {0,0,0,0}, xb = {0,0,0,0};
    if (prod) { xa = *(const f32x4*)xbase; xb = *(const f32x4*)(xbase + 4); }

    __syncthreads();

    const size_t H0O = (size_t)TS*BB*H1D;
    const size_t C0O = H0O + (size_t)BB*H0D;
    const size_t H1O = C0O + (size_t)BB*H0D;
    const size_t C1O = H1O + (size_t)BB*H1D;

    #pragma unroll 1
    for (int t = 0; t < TS; ++t) {
        const int rp = t & 1;
        // ========== Phase 1: layer0, step t (waves 0-7, one slice each) ==========
        if (prod) {
            bf16x8 xf = cvt8(xa, xb);
            {   // prefetch x(t+1)
                const int tn = (t + 1 < TS) ? (t + 1) : t;
                const float* xp = xbase + (size_t)tn * (BB*IND);
                xa = *(const f32x4*)xp; xb = *(const f32x4*)(xp + 4);
            }
            bf16x8 hf[4];
            #pragma unroll
            for (int ks = 0; ks < 4; ++ks)
                hf[ks] = ld8(&h0f[rp][arow][ks*32 + fk*8]);

            const int u = w*16 + fr;
            f32x4 ag[5];
            #pragma unroll
            for (int g = 0; g < 4; ++g) {
                const float b = BZ[g];
                f32x4 a = {b, b, b, b};
                a = mfma16(xf, WF[g*5], a);
                #pragma unroll
                for (int ks = 0; ks < 4; ++ks)
                    a = mfma16(hf[ks], WF[g*5 + 1 + ks], a);
                ag[g] = a;
            }
            {
                const float b = BZ[4];
                f32x4 a = {b, b, b, b};
                ag[4] = mfma16(xf, WF[20], a);
            }
            // lane's element: batch row fk (C row 4*fk -> reg 0), unit u
            const float i_ = sigm(ag[0][0]);
            const float f_ = sigm(ag[1][0]);
            const float g_ = tanh_f(ag[2][0]);
            const float o_ = sigm(ag[3][0]);
            const float c  = fmaf(f_, CS, i_ * g_);
            CS = c;
            const float hn = fmaf(o_, tanh_f(c), ag[4][0]);   // pre-clip state
            const float iv = fminf(fmaxf(hn, -10.f), 10.f);   // layer1 input
            h0f[rp ^ 1][fk][u] = hn;     // fp32 dword: one writer lane each
            i1f[rp ^ 1][fk][u] = iv;
            if (t == TS - 1) {
                out[H0O + (size_t)(row0 + fk)*H0D + u] = hn;
                out[C0O + (size_t)(row0 + fk)*H0D + u] = c;
            }
        }
        __syncthreads();   // B1: i1f[rp^1] ready; producers run ahead after this

        // ========== Phase 2: layer1, step t (waves 8-11) ==========
        if (!prod) {
            bf16x8 pf[4], hq[2];
            #pragma unroll
            for (int ks = 0; ks < 4; ++ks)
                pf[ks] = ld8(&i1f[rp ^ 1][arow][ks*32 + fk*8]);
            #pragma unroll
            for (int k2 = 0; k2 < 2; ++k2)
                hq[k2] = ld8(&h1q[rp][arow][k2*32 + fk*8]);

            const int u1 = (w - 8)*16 + fr;
            f32x4 a1[5];
            #pragma unroll
            for (int g = 0; g < 4; ++g) {
                const float b = BZ[g];
                f32x4 a = {b, b, b, b};
                #pragma unroll
                for (int ks = 0; ks < 4; ++ks)
                    a = mfma16(pf[ks], WF[g*6 + ks], a);
                #pragma unroll
                for (int k2 = 0; k2 < 2; ++k2)
                    a = mfma16(hq[k2], WF[g*6 + 4 + k2], a);
                a1[g] = a;
            }
            {
                const float b = BZ[4];
                f32x4 a = {b, b, b, b};
                #pragma unroll
                for (int ks = 0; ks < 4; ++ks)
                    a = mfma16(pf[ks], WF[24 + ks], a);
                a1[4] = a;
            }
            const float i_ = sigm(a1[0][0]);
            const float f_ = sigm(a1[1][0]);
            const float g_ = tanh_f(a1[2][0]);
            const float o_ = sigm(a1[3][0]);
            const float c  = fmaf(f_, CS, i_ * g_);
            CS = c;
            const float hn = fmaf(o_, tanh_f(c), a1[4][0]);   // pre-clip state
            const float yv = fminf(fmaxf(hn, -10.f), 10.f);
            out[((size_t)t*BB + row0 + fk)*H1D + u1] = yv;
            h1q[rp ^ 1][fk][u1] = hn;
            if (t == TS - 1) {
                out[H1O + (size_t)(row0 + fk)*H1D + u1] = hn;
                out[C1O + (size_t)(row0 + fk)*H1D + u1] = c;
            }
        }
        // no trailing barrier: next step's producer writes land in buffers
        // disjoint from this step's consumer reads; distance-2 reuse is
        // fenced by B1(t+1) (compiler drains lgkmcnt before s_barrier).
    }
}

} // namespace

extern "C" void kernel_launch(void* const* d_in, const int* in_sizes, int n_in,
                              void* d_out, int out_size, void* d_ws, size_t ws_size,
                              hipStream_t stream) {
    (void)in_sizes; (void)n_in; (void)d_ws; (void)ws_size; (void)out_size;
    const float* x    = (const float*)d_in[0];
    const float* h0i  = (const float*)d_in[1];
    const float* c0i  = (const float*)d_in[2];
    const float* h1i  = (const float*)d_in[3];
    const float* c1i  = (const float*)d_in[4];
    const float* Wih0 = (const float*)d_in[5];
    const float* Whh0 = (const float*)d_in[6];
    const float* bih0 = (const float*)d_in[7];
    const float* bhh0 = (const float*)d_in[8];
    const float* Ws0  = (const float*)d_in[9];
    const float* bs0  = (const float*)d_in[10];
    const float* Wih1 = (const float*)d_in[11];
    const float* Whh1 = (const float*)d_in[12];
    const float* bih1 = (const float*)d_in[13];
    const float* bhh1 = (const float*)d_in[14];
    const float* Ws1  = (const float*)d_in[15];
    const float* bs1  = (const float*)d_in[16];

    resid_lstm<<<dim3(BB / RPW), dim3(NT), 0, stream>>>(
        x, h0i, c0i, h1i, c1i,
        Wih0, Whh0, bih0, bhh0, Ws0, bs0,
        Wih1, Whh1, bih1, bhh1, Ws1, bs1,
        (float*)d_out);
}

// Round 13
// 631.851 us; speedup vs baseline: 1.2387x; 1.2387x over previous
//
#include <hip/hip_runtime.h>
#include <cstdint>
#include <cstddef>

namespace {

constexpr int TS  = 512;   // timesteps
constexpr int BB  = 1024;  // batch
constexpr int IND = 32;    // input dim
constexpr int H0D = 128;   // layer0 hidden
constexpr int H1D = 64;    // layer1 hidden
constexpr int RPW = 4;     // batch rows per WG -> 256 WGs = 1 block/CU
constexpr int S0u = 144;   // ushort stride, 128-wide bf16 state row (288B): reads <=2-way
constexpr int S1u = 80;    // ushort stride, 64-wide bf16 state row (160B)

typedef float f32x4 __attribute__((ext_vector_type(4)));
typedef __bf16 bf16x8 __attribute__((ext_vector_type(8)));

__device__ __forceinline__ float rcpf(float x) {
    float r; asm("v_rcp_f32 %0, %1" : "=v"(r) : "v"(x)); return r;
}
__device__ __forceinline__ float sigm(float z) { return rcpf(1.0f + __expf(-z)); }
__device__ __forceinline__ float tanh_f(float z) {
    return fmaf(-2.0f, rcpf(__expf(2.0f * z) + 1.0f), 1.0f);  // inf-safe both ends
}
__device__ __forceinline__ bf16x8 cvt8(f32x4 a, f32x4 b) {
    bf16x8 r;
    r[0] = (__bf16)a[0]; r[1] = (__bf16)a[1]; r[2] = (__bf16)a[2]; r[3] = (__bf16)a[3];
    r[4] = (__bf16)b[0]; r[5] = (__bf16)b[1]; r[6] = (__bf16)b[2]; r[7] = (__bf16)b[3];
    return r;
}
__device__ __forceinline__ bf16x8 ld8(const float* p) {
    f32x4 a = *(const f32x4*)p;
    f32x4 b = *(const f32x4*)(p + 4);
    return cvt8(a, b);
}
__device__ __forceinline__ f32x4 mfma16(bf16x8 a, bf16x8 b, f32x4 c) {
    return __builtin_amdgcn_mfma_f32_16x16x32_bf16(a, b, c, 0, 0, 0);
}
__device__ __forceinline__ unsigned short bfbits(float f) {
    __bf16 b = (__bf16)f;                 // native RNE cast, same as cvt8
    return __builtin_bit_cast(unsigned short, b);
}

// 256 WGs x 4 batch rows, 8 waves, 1 block/CU. R9-verified skeleton (602us):
// ONE barrier per step, producer waves 0-3 (layer0, 2 slices, step t) /
// consumer waves 4-7 (layer1 full-K, step t), producers run ahead into t+1.
// SINGLE change vs R9: state stored as PACKED BF16 (cvt moved from the
// fragment-read path to the write path -> bit-identical math, 48/32 fewer
// serial v_cvt on consumer/producer critical paths; fragment loads become
// one ds_read_b128 each). Dword-collapse bug class (R7/R8) avoided by
// construction: lane pairs exchange via __shfl_xor(1) and exactly ONE lane
// writes each packed dword (even fr -> h dword, odd fr -> i1 dword).
__global__ __launch_bounds__(512, 2) void resid_lstm(
    const float* __restrict__ x,
    const float* __restrict__ h0i, const float* __restrict__ c0i,
    const float* __restrict__ h1i, const float* __restrict__ c1i,
    const float* __restrict__ Wih0, const float* __restrict__ Whh0,
    const float* __restrict__ bih0, const float* __restrict__ bhh0,
    const float* __restrict__ Ws0,  const float* __restrict__ bs0v,
    const float* __restrict__ Wih1, const float* __restrict__ Whh1,
    const float* __restrict__ bih1, const float* __restrict__ bhh1,
    const float* __restrict__ Ws1,  const float* __restrict__ bs1v,
    float* __restrict__ out)
{
    const int tid  = threadIdx.x;
    const int lane = tid & 63;
    const int w    = tid >> 6;        // wave 0..7
    const int fr   = lane & 15;       // A-row index within tile / C col (unit)
    const int fk   = lane >> 4;       // k-group; also this lane's batch row
    const int row0 = blockIdx.x * RPW;
    const bool prod = (w < 4);

    __shared__ __align__(16) unsigned short h0b[2][RPW * S0u];  // h0, bf16
    __shared__ __align__(16) unsigned short i1b[2][RPW * S0u];  // clip(h0), bf16
    __shared__ __align__(16) unsigned short h1b[2][RPW * S1u];  // h1, bf16

    // zero ALL LDS first (separate barrier so init writes can't race it)
    for (int i = tid; i < 2 * RPW * S0u; i += 512) {
        (&h0b[0][0])[i] = 0;
        (&i1b[0][0])[i] = 0;
    }
    for (int i = tid; i < 2 * RPW * S1u; i += 512)
        (&h1b[0][0])[i] = 0;
    __syncthreads();

    bf16x8 WF[42];    // producer: 42 frags (2 slices x (4 gates x 5 + ws0));
                      // consumer: 28 frags (4 gates x 6 + ws1 x 4)
    float BZ[10];     // folded biases
    float CS[2];      // c-state: producer c0[slice 0,1]; consumer c1 in CS[0]
    CS[0] = 0.f; CS[1] = 0.f;

    if (prod) {
        #pragma unroll
        for (int sl = 0; sl < 2; ++sl) {
            const int u = (w + 4*sl)*16 + fr;
            #pragma unroll
            for (int g = 0; g < 4; ++g) {
                const int r0 = g*H0D + u;             // gate order i,f,g,o
                WF[sl*21 + g*5] = ld8(Wih0 + r0*IND + fk*8);
                #pragma unroll
                for (int ks = 0; ks < 4; ++ks)
                    WF[sl*21 + g*5 + 1 + ks] = ld8(Whh0 + r0*H0D + ks*32 + fk*8);
                BZ[sl*5 + g] = bih0[r0] + bhh0[r0];
            }
            WF[sl*21 + 20] = ld8(Ws0 + u*IND + fk*8);
            BZ[sl*5 + 4] = bs0v[u];
            CS[sl] = c0i[(size_t)(row0 + fk)*H0D + u];
        }
    } else {
        const int u1 = (w - 4)*16 + fr;
        #pragma unroll
        for (int g = 0; g < 4; ++g) {
            const int r1 = g*H1D + u1;
            #pragma unroll
            for (int ks = 0; ks < 4; ++ks)
                WF[g*6 + ks] = ld8(Wih1 + r1*H0D + ks*32 + fk*8);
            #pragma unroll
            for (int k2 = 0; k2 < 2; ++k2)
                WF[g*6 + 4 + k2] = ld8(Whh1 + r1*H1D + k2*32 + fk*8);
            BZ[g] = bih1[r1] + bhh1[r1];
        }
        #pragma unroll
        for (int ks = 0; ks < 4; ++ks)
            WF[24 + ks] = ld8(Ws1 + u1*H0D + ks*32 + fk*8);
        BZ[4] = bs1v[u1];
        CS[0] = c1i[(size_t)(row0 + fk)*H1D + u1];
    }

    // initial hidden states -> packed bf16 LDS, ONE writer per dword
    if (tid < RPW * H0D / 2) {
        const int r2 = tid >> 6, m = tid & 63;       // units 2m, 2m+1
        const unsigned lo = bfbits(h0i[(size_t)(row0 + r2)*H0D + 2*m]);
        const unsigned hi = bfbits(h0i[(size_t)(row0 + r2)*H0D + 2*m + 1]);
        *(unsigned*)&h0b[0][r2 * S0u + 2*m] = lo | (hi << 16);
    }
    if (tid < RPW * H1D / 2) {
        const int r2 = tid >> 5, m = tid & 31;       // units 2m, 2m+1
        const unsigned lo = bfbits(h1i[(size_t)(row0 + r2)*H1D + 2*m]);
        const unsigned hi = bfbits(h1i[(size_t)(row0 + r2)*H1D + 2*m + 1]);
        *(unsigned*)&h1b[0][r2 * S1u + 2*m] = lo | (hi << 16);
    }

    const int arow = fr >> 2;   // this lane's A-row batch index (rows duplicated x4)

    const float* xbase = x + ((size_t)row0 + arow)*IND + fk*8;
    f32x4 xa = {0,0,0,0}, xb = {0,0,0,0};
    if (prod) { xa = *(const f32x4*)xbase; xb = *(const f32x4*)(xbase + 4); }

    __syncthreads();

    const size_t H0O = (size_t)TS*BB*H1D;
    const size_t C0O = H0O + (size_t)BB*H0D;
    const size_t H1O = C0O + (size_t)BB*H0D;
    const size_t C1O = H1O + (size_t)BB*H1D;

    #pragma unroll 1
    for (int t = 0; t < TS; ++t) {
        const int rp = t & 1;
        // ========== Phase 1: layer0, step t (waves 0-3) ==========
        if (prod) {
            bf16x8 xf = cvt8(xa, xb);
            {   // prefetch x(t+1)
                const int tn = (t + 1 < TS) ? (t + 1) : t;
                const float* xp = xbase + (size_t)tn * (BB*IND);
                xa = *(const f32x4*)xp; xb = *(const f32x4*)(xp + 4);
            }
            bf16x8 hf[4];   // direct b128 fragment loads, zero cvt
            #pragma unroll
            for (int ks = 0; ks < 4; ++ks)
                hf[ks] = *(const bf16x8*)&h0b[rp][arow*S0u + ks*32 + fk*8];

            #pragma unroll
            for (int sl = 0; sl < 2; ++sl) {
                const int u = (w + 4*sl)*16 + fr;
                f32x4 ag[5];
                #pragma unroll
                for (int g = 0; g < 4; ++g) {
                    const float b = BZ[sl*5 + g];
                    f32x4 a = {b, b, b, b};
                    a = mfma16(xf, WF[sl*21 + g*5], a);
                    #pragma unroll
                    for (int ks = 0; ks < 4; ++ks)
                        a = mfma16(hf[ks], WF[sl*21 + g*5 + 1 + ks], a);
                    ag[g] = a;
                }
                {
                    const float b = BZ[sl*5 + 4];
                    f32x4 a = {b, b, b, b};
                    ag[4] = mfma16(xf, WF[sl*21 + 20], a);
                }
                // lane's element: batch row fk (C row 4*fk -> reg 0), unit u
                const float i_ = sigm(ag[0][0]);
                const float f_ = sigm(ag[1][0]);
                const float g_ = tanh_f(ag[2][0]);
                const float o_ = sigm(ag[3][0]);
                const float c  = fmaf(f_, CS[sl], i_ * g_);
                CS[sl] = c;
                const float hn = fmaf(o_, tanh_f(c), ag[4][0]);   // pre-clip state
                const float iv = fminf(fmaxf(hn, -10.f), 10.f);   // layer1 input
                // paired-lane bf16 pack: ONE writer per dword
                const unsigned hb = bfbits(hn), ib = bfbits(iv);
                const unsigned hp = (unsigned)__shfl_xor((int)hb, 1);
                const unsigned ip = (unsigned)__shfl_xor((int)ib, 1);
                if ((fr & 1) == 0) {        // u even: write h dword [u, u+1]
                    *(unsigned*)&h0b[rp ^ 1][fk*S0u + u] = hb | (hp << 16);
                } else {                    // u odd: write i1 dword [u-1, u]
                    *(unsigned*)&i1b[rp ^ 1][fk*S0u + (u - 1)] = ip | (ib << 16);
                }
                if (t == TS - 1) {
                    out[H0O + (size_t)(row0 + fk)*H0D + u] = hn;
                    out[C0O + (size_t)(row0 + fk)*H0D + u] = c;
                }
            }
        }
        __syncthreads();   // B1: i1b[rp^1] ready; producers run ahead after this

        // ========== Phase 2: layer1, step t (waves 4-7) ==========
        if (!prod) {
            bf16x8 pf[4], hq[2];   // direct b128 fragment loads, zero cvt
            #pragma unroll
            for (int ks = 0; ks < 4; ++ks)
                pf[ks] = *(const bf16x8*)&i1b[rp ^ 1][arow*S0u + ks*32 + fk*8];
            #pragma unroll
            for (int k2 = 0; k2 < 2; ++k2)
                hq[k2] = *(const bf16x8*)&h1b[rp][arow*S1u + k2*32 + fk*8];

            const int u1 = (w - 4)*16 + fr;
            f32x4 a1[5];
            #pragma unroll
            for (int g = 0; g < 4; ++g) {
                const float b = BZ[g];
                f32x4 a = {b, b, b, b};
                #pragma unroll
                for (int ks = 0; ks < 4; ++ks)
                    a = mfma16(pf[ks], WF[g*6 + ks], a);
                #pragma unroll
                for (int k2 = 0; k2 < 2; ++k2)
                    a = mfma16(hq[k2], WF[g*6 + 4 + k2], a);
                a1[g] = a;
            }
            {
                const float b = BZ[4];
                f32x4 a = {b, b, b, b};
                #pragma unroll
                for (int ks = 0; ks < 4; ++ks)
                    a = mfma16(pf[ks], WF[24 + ks], a);
                a1[4] = a;
            }
            const float i_ = sigm(a1[0][0]);
            const float f_ = sigm(a1[1][0]);
            const float g_ = tanh_f(a1[2][0]);
            const float o_ = sigm(a1[3][0]);
            const float c  = fmaf(f_, CS[0], i_ * g_);
            CS[0] = c;
            const float hn = fmaf(o_, tanh_f(c), a1[4][0]);   // pre-clip state
            const float yv = fminf(fmaxf(hn, -10.f), 10.f);
            out[((size_t)t*BB + row0 + fk)*H1D + u1] = yv;
            {   // paired-lane bf16 pack, even lane writes dword [u1, u1+1]
                const unsigned hb = bfbits(hn);
                const unsigned hp = (unsigned)__shfl_xor((int)hb, 1);
                if ((fr & 1) == 0)
                    *(unsigned*)&h1b[rp ^ 1][fk*S1u + u1] = hb | (hp << 16);
            }
            if (t == TS - 1) {
                out[H1O + (size_t)(row0 + fk)*H1D + u1] = hn;
                out[C1O + (size_t)(row0 + fk)*H1D + u1] = c;
            }
        }
        // no trailing barrier: next step's producer writes land in buffers
        // disjoint from this step's consumer reads; distance-2 reuse is
        // fenced by B1(t+1) (compiler drains lgkmcnt before s_barrier).
    }
}

} // namespace

extern "C" void kernel_launch(void* const* d_in, const int* in_sizes, int n_in,
                              void* d_out, int out_size, void* d_ws, size_t ws_size,
                              hipStream_t stream) {
    (void)in_sizes; (void)n_in; (void)d_ws; (void)ws_size; (void)out_size;
    const float* x    = (const float*)d_in[0];
    const float* h0i  = (const float*)d_in[1];
    const float* c0i  = (const float*)d_in[2];
    const float* h1i  = (const float*)d_in[3];
    const float* c1i  = (const float*)d_in[4];
    const float* Wih0 = (const float*)d_in[5];
    const float* Whh0 = (const float*)d_in[6];
    const float* bih0 = (const float*)d_in[7];
    const float* bhh0 = (const float*)d_in[8];
    const float* Ws0  = (const float*)d_in[9];
    const float* bs0  = (const float*)d_in[10];
    const float* Wih1 = (const float*)d_in[11];
    const float* Whh1 = (const float*)d_in[12];
    const float* bih1 = (const float*)d_in[13];
    const float* bhh1 = (const float*)d_in[14];
    const float* Ws1  = (const float*)d_in[15];
    const float* bs1  = (const float*)d_in[16];

    resid_lstm<<<dim3(BB / RPW), dim3(512), 0, stream>>>(
        x, h0i, c0i, h1i, c1i,
        Wih0, Whh0, bih0, bhh0, Ws0, bs0,
        Wih1, Whh1, bih1, bhh1, Ws1, bs1,
        (float*)d_out);
}

// Round 14
// 599.012 us; speedup vs baseline: 1.3066x; 1.0548x over previous
//
#include <hip/hip_runtime.h>
#include <cstdint>
#include <cstddef>

namespace {

constexpr int TS  = 512;   // timesteps
constexpr int BB  = 1024;  // batch
constexpr int IND = 32;    // input dim
constexpr int H0D = 128;   // layer0 hidden
constexpr int H1D = 64;    // layer1 hidden
constexpr int RPW = 4;     // batch rows per WG -> 256 WGs = 1 block/CU
constexpr int S0  = 132;   // padded LDS row stride (floats) for 128-wide state
constexpr int S1  = 68;    // padded LDS row stride (floats) for 64-wide state

typedef float f32x4 __attribute__((ext_vector_type(4)));
typedef __bf16 bf16x8 __attribute__((ext_vector_type(8)));

__device__ __forceinline__ float rcpf(float x) {
    float r; asm("v_rcp_f32 %0, %1" : "=v"(r) : "v"(x)); return r;
}
__device__ __forceinline__ float sigm(float z) { return rcpf(1.0f + __expf(-z)); }
__device__ __forceinline__ float tanh_f(float z) {
    return fmaf(-2.0f, rcpf(__expf(2.0f * z) + 1.0f), 1.0f);  // inf-safe both ends
}
__device__ __forceinline__ bf16x8 cvt8(f32x4 a, f32x4 b) {
    bf16x8 r;
    r[0] = (__bf16)a[0]; r[1] = (__bf16)a[1]; r[2] = (__bf16)a[2]; r[3] = (__bf16)a[3];
    r[4] = (__bf16)b[0]; r[5] = (__bf16)b[1]; r[6] = (__bf16)b[2]; r[7] = (__bf16)b[3];
    return r;
}
__device__ __forceinline__ bf16x8 ld8(const float* p) {
    f32x4 a = *(const f32x4*)p;
    f32x4 b = *(const f32x4*)(p + 4);
    return cvt8(a, b);
}
__device__ __forceinline__ f32x4 mfma16(bf16x8 a, bf16x8 b, f32x4 c) {
    return __builtin_amdgcn_mfma_f32_16x16x32_bf16(a, b, c, 0, 0, 0);
}

// Relaxed barrier: order LDS (lgkmcnt) ONLY, leave global loads/stores in
// flight across the barrier (T4: never vmcnt(0) in the main loop). The
// compiler still inserts vmcnt waits before actual USE of loaded x regs,
// a full step (~2900 cy) later. sched_barrier(0) fences against rule #18
// (hipcc hoisting register-only ops past inline-asm waitcnt).
__device__ __forceinline__ void lds_barrier() {
    asm volatile("s_waitcnt lgkmcnt(0)" ::: "memory");
    __builtin_amdgcn_s_barrier();
    __builtin_amdgcn_sched_barrier(0);
}

// 256 WGs x 4 batch rows, 8 waves, 1 block/CU. R9-verified skeleton (602us):
// fp32 padded LDS state (one writer lane per dword), ONE barrier per step,
// producer waves 0-3 (layer0, 2 slices, step t) / consumer waves 4-7
// (layer1 full-K, step t), producers run ahead into t+1 after B1.
// SINGLE change vs R9: main-loop __syncthreads() -> lds_barrier() so the
// x-prefetch (HBM ~900cy) and y-stores are NOT drained at every barrier
// (the m97 "s_waitcnt vmcnt(0) before s_barrier" stall, 512x per kernel).
__global__ __launch_bounds__(512, 2) void resid_lstm(
    const float* __restrict__ x,
    const float* __restrict__ h0i, const float* __restrict__ c0i,
    const float* __restrict__ h1i, const float* __restrict__ c1i,
    const float* __restrict__ Wih0, const float* __restrict__ Whh0,
    const float* __restrict__ bih0, const float* __restrict__ bhh0,
    const float* __restrict__ Ws0,  const float* __restrict__ bs0v,
    const float* __restrict__ Wih1, const float* __restrict__ Whh1,
    const float* __restrict__ bih1, const float* __restrict__ bhh1,
    const float* __restrict__ Ws1,  const float* __restrict__ bs1v,
    float* __restrict__ out)
{
    const int tid  = threadIdx.x;
    const int lane = tid & 63;
    const int w    = tid >> 6;        // wave 0..7
    const int fr   = lane & 15;       // A-row index within tile / C col (unit)
    const int fk   = lane >> 4;       // k-group; also this lane's batch row
    const int row0 = blockIdx.x * RPW;
    const bool prod = (w < 4);

    __shared__ __align__(16) float h0f[2][RPW][S0];   // h0 state (fp32)
    __shared__ __align__(16) float i1f[2][RPW][S0];   // clip(h0) (fp32)
    __shared__ __align__(16) float h1q[2][RPW][S1];   // h1 state (fp32)

    // zero ALL LDS first (separate barrier so init writes can't race it)
    for (int i = tid; i < 2 * RPW * S0; i += 512) {
        (&h0f[0][0][0])[i] = 0.f;
        (&i1f[0][0][0])[i] = 0.f;
    }
    for (int i = tid; i < 2 * RPW * S1; i += 512)
        (&h1q[0][0][0])[i] = 0.f;
    __syncthreads();

    bf16x8 WF[42];    // producer: 42 frags (2 slices x (4 gates x 5 + ws0));
                      // consumer: 28 frags (4 gates x 6 + ws1 x 4)
    float BZ[10];     // folded biases
    float CS[2];      // c-state: producer c0[slice 0,1]; consumer c1 in CS[0]
    CS[0] = 0.f; CS[1] = 0.f;

    if (prod) {
        #pragma unroll
        for (int sl = 0; sl < 2; ++sl) {
            const int u = (w + 4*sl)*16 + fr;
            #pragma unroll
            for (int g = 0; g < 4; ++g) {
                const int r0 = g*H0D + u;             // gate order i,f,g,o
                WF[sl*21 + g*5] = ld8(Wih0 + r0*IND + fk*8);
                #pragma unroll
                for (int ks = 0; ks < 4; ++ks)
                    WF[sl*21 + g*5 + 1 + ks] = ld8(Whh0 + r0*H0D + ks*32 + fk*8);
                BZ[sl*5 + g] = bih0[r0] + bhh0[r0];
            }
            WF[sl*21 + 20] = ld8(Ws0 + u*IND + fk*8);
            BZ[sl*5 + 4] = bs0v[u];
            CS[sl] = c0i[(size_t)(row0 + fk)*H0D + u];
        }
    } else {
        const int u1 = (w - 4)*16 + fr;
        #pragma unroll
        for (int g = 0; g < 4; ++g) {
            const int r1 = g*H1D + u1;
            #pragma unroll
            for (int ks = 0; ks < 4; ++ks)
                WF[g*6 + ks] = ld8(Wih1 + r1*H0D + ks*32 + fk*8);
            #pragma unroll
            for (int k2 = 0; k2 < 2; ++k2)
                WF[g*6 + 4 + k2] = ld8(Whh1 + r1*H1D + k2*32 + fk*8);
            BZ[g] = bih1[r1] + bhh1[r1];
        }
        #pragma unroll
        for (int ks = 0; ks < 4; ++ks)
            WF[24 + ks] = ld8(Ws1 + u1*H0D + ks*32 + fk*8);
        BZ[4] = bs1v[u1];
        CS[0] = c1i[(size_t)(row0 + fk)*H1D + u1];
    }

    // initial hidden states -> LDS fp32 (both read at t=0 from buffer 0)
    {
        const int u = tid & 127, b2 = tid >> 7;
        h0f[0][b2][u] = h0i[(size_t)(row0 + b2)*H0D + u];
    }
    if (tid < RPW * H1D) {
        const int u = tid & 63, b2 = tid >> 6;
        h1q[0][b2][u] = h1i[(size_t)(row0 + b2)*H1D + u];
    }

    const int arow = fr >> 2;   // this lane's A-row batch index (rows duplicated x4)

    const float* xbase = x + ((size_t)row0 + arow)*IND + fk*8;
    f32x4 xa = {0,0,0,0}, xb = {0,0,0,0};
    if (prod) { xa = *(const f32x4*)xbase; xb = *(const f32x4*)(xbase + 4); }

    __syncthreads();

    const size_t H0O = (size_t)TS*BB*H1D;
    const size_t C0O = H0O + (size_t)BB*H0D;
    const size_t H1O = C0O + (size_t)BB*H0D;
    const size_t C1O = H1O + (size_t)BB*H1D;

    #pragma unroll 1
    for (int t = 0; t < TS; ++t) {
        const int rp = t & 1;
        // ========== Phase 1: layer0, step t (waves 0-3) ==========
        if (prod) {
            bf16x8 xf = cvt8(xa, xb);
            {   // prefetch x(t+1); stays in flight across the relaxed barrier
                const int tn = (t + 1 < TS) ? (t + 1) : t;
                const float* xp = xbase + (size_t)tn * (BB*IND);
                xa = *(const f32x4*)xp; xb = *(const f32x4*)(xp + 4);
            }
            bf16x8 hf[4];
            #pragma unroll
            for (int ks = 0; ks < 4; ++ks)
                hf[ks] = ld8(&h0f[rp][arow][ks*32 + fk*8]);

            #pragma unroll
            for (int sl = 0; sl < 2; ++sl) {
                const int u = (w + 4*sl)*16 + fr;
                f32x4 ag[5];
                #pragma unroll
                for (int g = 0; g < 4; ++g) {
                    const float b = BZ[sl*5 + g];
                    f32x4 a = {b, b, b, b};
                    a = mfma16(xf, WF[sl*21 + g*5], a);
                    #pragma unroll
                    for (int ks = 0; ks < 4; ++ks)
                        a = mfma16(hf[ks], WF[sl*21 + g*5 + 1 + ks], a);
                    ag[g] = a;
                }
                {
                    const float b = BZ[sl*5 + 4];
                    f32x4 a = {b, b, b, b};
                    ag[4] = mfma16(xf, WF[sl*21 + 20], a);
                }
                // lane's element: batch row fk (C row 4*fk -> reg 0), unit u
                const float i_ = sigm(ag[0][0]);
                const float f_ = sigm(ag[1][0]);
                const float g_ = tanh_f(ag[2][0]);
                const float o_ = sigm(ag[3][0]);
                const float c  = fmaf(f_, CS[sl], i_ * g_);
                CS[sl] = c;
                const float hn = fmaf(o_, tanh_f(c), ag[4][0]);   // pre-clip state
                const float iv = fminf(fmaxf(hn, -10.f), 10.f);   // layer1 input
                h0f[rp ^ 1][fk][u] = hn;     // fp32 dword: one writer lane each
                i1f[rp ^ 1][fk][u] = iv;
                if (t == TS - 1) {
                    out[H0O + (size_t)(row0 + fk)*H0D + u] = hn;
                    out[C0O + (size_t)(row0 + fk)*H0D + u] = c;
                }
            }
        }
        lds_barrier();   // B1: LDS-ordered only; vmem stays in flight

        // ========== Phase 2: layer1, step t (waves 4-7) ==========
        if (!prod) {
            bf16x8 pf[4], hq[2];
            #pragma unroll
            for (int ks = 0; ks < 4; ++ks)
                pf[ks] = ld8(&i1f[rp ^ 1][arow][ks*32 + fk*8]);
            #pragma unroll
            for (int k2 = 0; k2 < 2; ++k2)
                hq[k2] = ld8(&h1q[rp][arow][k2*32 + fk*8]);

            const int u1 = (w - 4)*16 + fr;
            f32x4 a1[5];
            #pragma unroll
            for (int g = 0; g < 4; ++g) {
                const float b = BZ[g];
                f32x4 a = {b, b, b, b};
                #pragma unroll
                for (int ks = 0; ks < 4; ++ks)
                    a = mfma16(pf[ks], WF[g*6 + ks], a);
                #pragma unroll
                for (int k2 = 0; k2 < 2; ++k2)
                    a = mfma16(hq[k2], WF[g*6 + 4 + k2], a);
                a1[g] = a;
            }
            {
                const float b = BZ[4];
                f32x4 a = {b, b, b, b};
                #pragma unroll
                for (int ks = 0; ks < 4; ++ks)
                    a = mfma16(pf[ks], WF[24 + ks], a);
                a1[4] = a;
            }
            const float i_ = sigm(a1[0][0]);
            const float f_ = sigm(a1[1][0]);
            const float g_ = tanh_f(a1[2][0]);
            const float o_ = sigm(a1[3][0]);
            const float c  = fmaf(f_, CS[0], i_ * g_);
            CS[0] = c;
            const float hn = fmaf(o_, tanh_f(c), a1[4][0]);   // pre-clip state
            const float yv = fminf(fmaxf(hn, -10.f), 10.f);
            out[((size_t)t*BB + row0 + fk)*H1D + u1] = yv;   // store stays in flight
            h1q[rp ^ 1][fk][u1] = hn;
            if (t == TS - 1) {
                out[H1O + (size_t)(row0 + fk)*H1D + u1] = hn;
                out[C1O + (size_t)(row0 + fk)*H1D + u1] = c;
            }
        }
        // no trailing barrier: next step's producer writes land in buffers
        // disjoint from this step's consumer reads; distance-2 reuse is
        // fenced by B1(t+1)'s lgkmcnt(0)+s_barrier.
    }
}

} // namespace

extern "C" void kernel_launch(void* const* d_in, const int* in_sizes, int n_in,
                              void* d_out, int out_size, void* d_ws, size_t ws_size,
                              hipStream_t stream) {
    (void)in_sizes; (void)n_in; (void)d_ws; (void)ws_size; (void)out_size;
    const float* x    = (const float*)d_in[0];
    const float* h0i  = (const float*)d_in[1];
    const float* c0i  = (const float*)d_in[2];
    const float* h1i  = (const float*)d_in[3];
    const float* c1i  = (const float*)d_in[4];
    const float* Wih0 = (const float*)d_in[5];
    const float* Whh0 = (const float*)d_in[6];
    const float* bih0 = (const float*)d_in[7];
    const float* bhh0 = (const float*)d_in[8];
    const float* Ws0  = (const float*)d_in[9];
    const float* bs0  = (const float*)d_in[10];
    const float* Wih1 = (const float*)d_in[11];
    const float* Whh1 = (const float*)d_in[12];
    const float* bih1 = (const float*)d_in[13];
    const float* bhh1 = (const float*)d_in[14];
    const float* Ws1  = (const float*)d_in[15];
    const float* bs1  = (const float*)d_in[16];

    resid_lstm<<<dim3(BB / RPW), dim3(512), 0, stream>>>(
        x, h0i, c0i, h1i, c1i,
        Wih0, Whh0, bih0, bhh0, Ws0, bs0,
        Wih1, Whh1, bih1, bhh1, Ws1, bs1,
        (float*)d_out);
}